// Round 9
// baseline (371.010 us; speedup 1.0000x reference)
//
#include <hip/hip_runtime.h>
#include <math.h>
#include <stdint.h>

#define NUM_CL 21
#define NB 4
#define H 512
#define W 512
#define PH 171
#define PW 171
#define PWPAD 176
#define NHH 169
#define NWW 169
#define M_TOT (NHH*NWW)          // 28561
#define NCP (NB*NUM_CL)          // 84
#define ACC_PAD 192              // padded per-(nc,chunk) stage stride
#define POS_ALPHA 5e-4
#define NBLKA (NB*NUM_CL*PH)     // 14364
#define SEGR 43                  // rows per segment (4 segs: 43,43,43,40)
#define GRID 256
#define AITERS ((NBLKA + GRID*2 - 1) / (GRID*2))   // 29

typedef unsigned long long u64;
typedef unsigned int u32;

__device__ __forceinline__ int upIdx(int lo, int hi) {
    return lo*9 - (lo*(lo-1))/2 + (hi - lo);
}
__device__ __forceinline__ int tri(int d, int e) { return d*(d+1)/2 + e; }

__device__ __forceinline__ float wred64(float v) {
    #pragma unroll
    for (int o = 32; o > 0; o >>= 1) v += __shfl_down(v, o, 64);
    return v;
}

// sum the 3 chunk partials for accumulator index k of problem t, in f64
__device__ __forceinline__ double rdacc(const float* __restrict__ st, int t, int k) {
    const float* b = st + (size_t)t * 3 * ACC_PAD + k;
    return (double)b[0] + (double)b[ACC_PAD] + (double)b[2*ACC_PAD];
}

// Device-scope sense barrier. cnt/rel zero-initialized by memset node.
// Co-residency guaranteed: 256 blocks, launch_bounds(256,2) => >=512 block slots.
__device__ __forceinline__ void gridBarrier(u32* cnt, u32* rel) {
    __syncthreads();
    if (threadIdx.x == 0) {
        __threadfence();     // prior global stores visible at device scope
        u32 old = __hip_atomic_fetch_add(cnt, 1u, __ATOMIC_ACQ_REL, __HIP_MEMORY_SCOPE_AGENT);
        if (old == GRID - 1) {
            __hip_atomic_store(rel, 1u, __ATOMIC_RELEASE, __HIP_MEMORY_SCOPE_AGENT);
        } else {
            while (__hip_atomic_load(rel, __ATOMIC_ACQUIRE, __HIP_MEMORY_SCOPE_AGENT) == 0u) {
                __builtin_amdgcn_s_sleep(8);
            }
        }
        __threadfence();
    }
    __syncthreads();
}

// ---------------- Mega kernel: A (BCE+pool) -> bar -> B (cov) -> bar -> C ----------------
__global__ __launch_bounds__(256, 2) void mega(
    const float* __restrict__ logits, const int* __restrict__ labels,
    float* __restrict__ pooledP, unsigned char* __restrict__ pooledL8,
    float* __restrict__ stage, float* __restrict__ bce_part,
    u32* __restrict__ cnt_part, u32* __restrict__ bar,
    float* __restrict__ out)
{
    int tid  = threadIdx.x;
    int half = tid >> 7;           // 0..1
    int th   = tid & 127;          // lane within half

    __shared__ float         svP[2][W];
    __shared__ unsigned char svL[2][W];
    __shared__ float         rb[256];
    __shared__ u32           rc[256];
    __shared__ float         red[4][108];

    // ================= Phase A =================
    float bce = 0.f;
    u32 cnt = 0;

    for (int it = 0; it < AITERS; ++it) {
        int task = (it*GRID + (int)blockIdx.x)*2 + half;
        bool act = task < NBLKA;
        int c = 0;
        size_t rowr = 0;
        float4 x4[3]; int4 l4[3];
        int rbase = 0;
        if (act) {
            c = task % NUM_CL;
            int t2 = task / NUM_CL;
            int ph = t2 % PH;
            int n  = t2 / PH;
            rowr = (size_t)(n*NUM_CL + c) * PH + ph;
            const float* lgp = logits + (size_t)(n*NUM_CL + c) * (H*W);
            const int*   lbp = labels + (size_t)n * (H*W);
            rbase = 3*ph - 1;
            int col0 = th << 2;
            #pragma unroll
            for (int rr = 0; rr < 3; ++rr) {
                int r = rbase + rr;
                if (r >= 0) {            // only ph==0 skips rr==0
                    x4[rr] = *(const float4*)(lgp + (size_t)r*W + col0);
                    l4[rr] = *(const int4*)  (lbp + (size_t)r*W + col0);
                }
            }
        }

        float vP[4] = {-INFINITY, -INFINITY, -INFINITY, -INFINITY};
        int   vL[4] = {0,0,0,0};
        if (act) {
            #pragma unroll
            for (int rr = 0; rr < 3; ++rr) {
                int r = rbase + rr;
                if (r < 0) continue;
                float xs[4] = {x4[rr].x, x4[rr].y, x4[rr].z, x4[rr].w};
                int   ls[4] = {l4[rr].x, l4[rr].y, l4[rr].z, l4[rr].w};
                #pragma unroll
                for (int k = 0; k < 4; ++k) {
                    int lab = ls[k];
                    float x = xs[k];
                    float m = (lab < NUM_CL) ? 1.f : 0.f;
                    float y = (lab == c) ? 1.f : 0.f;
                    float te = __expf(-fabsf(x));
                    float u  = 1.f + te;
                    float sp = __logf(u);                    // log1p(te)
                    float rcv = __builtin_amdgcn_rcpf(u);    // 1/(1+te)
                    bce += m * (fmaxf(x, 0.f) - x*y + sp);
                    float sig = (x >= 0.f) ? rcv : te*rcv;
                    vP[k] = fmaxf(vP[k], sig*m + 1e-6f);
                    vL[k] |= (lab == c);
                    if (c == 0) cnt += (u32)(lab < NUM_CL);
                }
            }
            ((float4*)svP[half])[th] = make_float4(vP[0], vP[1], vP[2], vP[3]);
            uchar4 u4;
            u4.x = (unsigned char)vL[0]; u4.y = (unsigned char)vL[1];
            u4.z = (unsigned char)vL[2]; u4.w = (unsigned char)vL[3];
            ((uchar4*)svL[half])[th] = u4;
        }
        __syncthreads();
        if (act) {
            #pragma unroll
            for (int pass = 0; pass < 2; ++pass) {
                int pw = th + pass*128;
                if (pw < PW) {
                    int c0 = 3*pw - 1; if (c0 < 0) c0 = 0;
                    int c1 = 3*pw + 2; if (c1 > W) c1 = W;
                    float pm = -INFINITY;
                    int lm = 0;
                    for (int qq = c0; qq < c1; ++qq) {
                        pm = fmaxf(pm, svP[half][qq]);
                        lm |= svL[half][qq];
                    }
                    pooledP [rowr * PWPAD + pw] = pm;
                    pooledL8[rowr * PWPAD + pw] = (unsigned char)lm;
                }
            }
        }
        __syncthreads();
    }

    // block reduce BCE / count
    rb[tid] = bce; rc[tid] = cnt;
    __syncthreads();
    #pragma unroll
    for (int s = 128; s > 0; s >>= 1) {
        if (tid < s) { rb[tid] += rb[tid + s]; rc[tid] += rc[tid + s]; }
        __syncthreads();
    }
    if (tid == 0) { bce_part[blockIdx.x] = rb[0]; cnt_part[blockIdx.x] = rc[0]; }

    gridBarrier(&bar[0], &bar[1]);

    // ================= Phase B =================
    for (int btask = (int)blockIdx.x; btask < NCP*6; btask += GRID) {
        int nc    = btask / 6;
        int rem   = btask - nc*6;
        int chunk = rem % 3;
        int grp   = rem / 3;
        int lane  = tid & 63;
        int seg   = tid >> 6;        // 0..3
        int j     = chunk*64 + lane;
        bool active = (j < NWW);
        int jc = active ? j : (NWW - 1);
        int i0 = seg * SEGR;
        int i1 = (seg == 3) ? NWW : (i0 + SEGR);

        const float* P = pooledP + (size_t)nc * PH * PWPAD + jc;
        const unsigned char* L = pooledL8 + (size_t)nc * PH * PWPAD + jc;
        float* st = stage + (size_t)(nc*3 + chunk) * ACC_PAD;

        float pA[3], pB[3], lA[3], lB[3];
        #pragma unroll
        for (int t = 0; t < 3; ++t) {
            pA[t] = P[(size_t)i0 * PWPAD + t];
            lA[t] = (float)L[(size_t)i0 * PWPAD + t];
            pB[t] = P[(size_t)(i0+1) * PWPAD + t];
            lB[t] = (float)L[(size_t)(i0+1) * PWPAD + t];
        }

        if (grp == 0) {
            float sl[9], sp[9], cll[45], cpp[45];
            #pragma unroll
            for (int d = 0; d < 9; ++d) { sl[d] = 0.f; sp[d] = 0.f; }
            #pragma unroll
            for (int k = 0; k < 45; ++k) { cll[k] = 0.f; cpp[k] = 0.f; }

            for (int i = i0; i < i1; ++i) {
                const float* rp = P + (size_t)(i+2) * PWPAD;
                const unsigned char* rl = L + (size_t)(i+2) * PWPAD;
                float pC[3] = {rp[0], rp[1], rp[2]};
                float lC[3] = {(float)rl[0], (float)rl[1], (float)rl[2]};
                float pv[9] = {pA[0],pA[1],pA[2], pB[0],pB[1],pB[2], pC[0],pC[1],pC[2]};
                float lv[9] = {lA[0],lA[1],lA[2], lB[0],lB[1],lB[2], lC[0],lC[1],lC[2]};
                #pragma unroll
                for (int d = 0; d < 9; ++d) { sp[d] += pv[d]; sl[d] += lv[d]; }
                int k = 0;
                #pragma unroll
                for (int d = 0; d < 9; ++d)
                    #pragma unroll
                    for (int e = d; e < 9; ++e) {
                        cpp[k] += pv[d]*pv[e];
                        cll[k] += lv[d]*lv[e];
                        ++k;
                    }
                #pragma unroll
                for (int t = 0; t < 3; ++t) {
                    pA[t] = pB[t]; pB[t] = pC[t];
                    lA[t] = lB[t]; lB[t] = lC[t];
                }
            }
            #pragma unroll
            for (int k = 0; k < 9; ++k) { float r = wred64(active ? sl[k] : 0.f); if (lane == 0) red[seg][k] = r; }
            #pragma unroll
            for (int k = 0; k < 9; ++k) { float r = wred64(active ? sp[k] : 0.f); if (lane == 0) red[seg][9+k] = r; }
            #pragma unroll
            for (int k = 0; k < 45; ++k) { float r = wred64(active ? cll[k] : 0.f); if (lane == 0) red[seg][18+k] = r; }
            __syncthreads();
            for (int k = tid; k < 63; k += 256)
                st[k] = red[0][k] + red[1][k] + red[2][k] + red[3][k];
            __syncthreads();
            #pragma unroll
            for (int k = 0; k < 45; ++k) { float r = wred64(active ? cpp[k] : 0.f); if (lane == 0) red[seg][k] = r; }
            __syncthreads();
            for (int k = tid; k < 45; k += 256)
                st[63 + k] = red[0][k] + red[1][k] + red[2][k] + red[3][k];
            __syncthreads();
        } else {
            float clp[81];
            #pragma unroll
            for (int k = 0; k < 81; ++k) clp[k] = 0.f;

            for (int i = i0; i < i1; ++i) {
                const float* rp = P + (size_t)(i+2) * PWPAD;
                const unsigned char* rl = L + (size_t)(i+2) * PWPAD;
                float pC[3] = {rp[0], rp[1], rp[2]};
                float lC[3] = {(float)rl[0], (float)rl[1], (float)rl[2]};
                float pv[9] = {pA[0],pA[1],pA[2], pB[0],pB[1],pB[2], pC[0],pC[1],pC[2]};
                float lv[9] = {lA[0],lA[1],lA[2], lB[0],lB[1],lB[2], lC[0],lC[1],lC[2]};
                #pragma unroll
                for (int d = 0; d < 9; ++d)
                    #pragma unroll
                    for (int e = 0; e < 9; ++e)
                        clp[d*9+e] += lv[d]*pv[e];
                #pragma unroll
                for (int t = 0; t < 3; ++t) {
                    pA[t] = pB[t]; pB[t] = pC[t];
                    lA[t] = lB[t]; lB[t] = lC[t];
                }
            }
            #pragma unroll
            for (int k = 0; k < 81; ++k) { float r = wred64(active ? clp[k] : 0.f); if (lane == 0) red[seg][k] = r; }
            __syncthreads();
            for (int k = tid; k < 81; k += 256)
                st[108 + k] = red[0][k] + red[1][k] + red[2][k] + red[3][k];
            __syncthreads();
        }
    }

    gridBarrier(&bar[2], &bar[3]);

    // ================= Phase C =================
    if (blockIdx.x == 0) {
        int t = tid;
        __shared__ double sb[256];
        __shared__ u32 sc2[256];
        double bs = 0.0; u32 cs = 0;
        for (int i = t; i < GRID; i += 256) { bs += (double)bce_part[i]; cs += cnt_part[i]; }
        sb[t] = bs; sc2[t] = cs;
        __syncthreads();
        #pragma unroll
        for (int s = 128; s > 0; s >>= 1) {
            if (t < s) { sb[t] += sb[t + s]; sc2[t] += sc2[t + s]; }
            __syncthreads();
        }

        float contrib = 0.f;
        if (t < NCP) {
            const double Minv = 1.0 / (double)M_TOT;
            double Sl[9], Sp[9];
            #pragma unroll
            for (int d = 0; d < 9; ++d) { Sl[d] = rdacc(stage, t, d); Sp[d] = rdacc(stage, t, 9+d); }

            float A[45], G[45], B[81];
            #pragma unroll
            for (int d = 0; d < 9; ++d) {
                #pragma unroll
                for (int e = 0; e <= d; ++e) {
                    int ku = upIdx(e, d);
                    double vp = rdacc(stage, t, 63+ku) - Sp[d]*Sp[e]*Minv;
                    double vl = rdacc(stage, t, 18+ku) - Sl[d]*Sl[e]*Minv;
                    if (d == e) vp += POS_ALPHA;
                    A[tri(d,e)] = (float)vp;
                    G[tri(d,e)] = (float)vl;
                }
            }
            #pragma unroll
            for (int d = 0; d < 9; ++d) {
                #pragma unroll
                for (int e = 0; e < 9; ++e)
                    B[d*9+e] = (float)(rdacc(stage, t, 108 + d*9 + e) - Sl[d]*Sp[e]*Minv);
            }

            // Cholesky of A (lower, in place)
            #pragma unroll
            for (int d = 0; d < 9; ++d) {
                float s = A[tri(d,d)];
                #pragma unroll
                for (int f = 0; f < d; ++f) { float v = A[tri(d,f)]; s -= v*v; }
                float ldd = sqrtf(s);
                A[tri(d,d)] = ldd;
                float inv = 1.f / ldd;
                #pragma unroll
                for (int e = d+1; e < 9; ++e) {
                    float s2 = A[tri(e,d)];
                    #pragma unroll
                    for (int f = 0; f < d; ++f) s2 -= A[tri(e,f)] * A[tri(d,f)];
                    A[tri(e,d)] = s2 * inv;
                }
            }

            // forward substitution
            #pragma unroll
            for (int d = 0; d < 9; ++d) {
                #pragma unroll
                for (int e = 0; e < 9; ++e) {
                    float s = B[d*9+e];
                    #pragma unroll
                    for (int f = 0; f < e; ++f) s -= A[tri(e,f)] * B[d*9+f];
                    B[d*9+e] = s / A[tri(e,e)];
                }
            }

            // appro_var = la_cov - W W^T + alpha*I
            #pragma unroll
            for (int d = 0; d < 9; ++d) {
                #pragma unroll
                for (int g = 0; g <= d; ++g) {
                    float qv = 0.f;
                    #pragma unroll
                    for (int e = 0; e < 9; ++e) qv += B[d*9+e] * B[g*9+e];
                    float v = G[tri(d,g)] - qv;
                    if (d == g) v += (float)POS_ALPHA;
                    G[tri(d,g)] = v;
                }
            }

            // Cholesky of G, sum log(diag + 1e-8)
            float sumlog = 0.f;
            #pragma unroll
            for (int d = 0; d < 9; ++d) {
                float s = G[tri(d,d)];
                #pragma unroll
                for (int f = 0; f < d; ++f) { float v = G[tri(d,f)]; s -= v*v; }
                float ldd = sqrtf(s);
                G[tri(d,d)] = ldd;
                sumlog += logf(ldd + 1e-8f);
                float inv = 1.f / ldd;
                #pragma unroll
                for (int e = d+1; e < 9; ++e) {
                    float s2 = G[tri(e,d)];
                    #pragma unroll
                    for (int f = 0; f < d; ++f) s2 -= G[tri(e,f)] * G[tri(d,f)];
                    G[tri(e,d)] = s2 * inv;
                }
            }
            contrib = sumlog * (1.0f / 36.0f);   // /(N * HALF_D) = /(4*9)
        }

        __shared__ float sred[256];
        sred[t] = contrib;
        __syncthreads();
        #pragma unroll
        for (int s = 128; s > 0; s >>= 1) {
            if (t < s) sred[t] += sred[t + s];
            __syncthreads();
        }
        if (t == 0) {
            double bce_loss = sb[0] / ((double)sc2[0] + 1.0);
            out[0] = (float)(0.5 * bce_loss + 0.5 * (double)sred[0]);
        }
    }
}

extern "C" void kernel_launch(void* const* d_in, const int* in_sizes, int n_in,
                              void* d_out, int out_size, void* d_ws, size_t ws_size,
                              hipStream_t stream)
{
    (void)in_sizes; (void)n_in; (void)out_size; (void)ws_size;
    const float* logits = (const float*)d_in[0];
    const int*   labels = (const int*)d_in[1];
    float* out = (float*)d_out;

    uint8_t* w = (uint8_t*)d_ws;
    size_t off = 0;
    u32* bar = (u32*)(w + off);                off += 64;                            // barrier words
    float* stage = (float*)(w + off);          off += (size_t)NCP * 3 * ACC_PAD * 4; // 193536
    float* bce_part = (float*)(w + off);       off += (size_t)GRID * 4;
    u32* cnt_part = (u32*)(w + off);           off += (size_t)GRID * 4;
    off = (off + 15) & ~(size_t)15;
    float* pooledP = (float*)(w + off);        off += (size_t)NCP * PH * PWPAD * 4;  // 10.1 MB
    unsigned char* pooledL8 = (unsigned char*)(w + off); off += (size_t)NCP * PH * PWPAD; // 2.5 MB

    hipMemsetAsync(bar, 0, 64, stream);
    mega<<<GRID, 256, 0, stream>>>(logits, labels, pooledP, pooledL8,
                                   stage, bce_part, cnt_part, bar, out);
}

// Round 10
// 199.747 us; speedup vs baseline: 1.8574x; 1.8574x over previous
//
#include <hip/hip_runtime.h>
#include <math.h>
#include <stdint.h>

#define NUM_CL 21
#define NB 4
#define H 512
#define W 512
#define PH 171
#define PW 171
#define PWPAD 176
#define NHH 169
#define NWW 169
#define M_TOT (NHH*NWW)          // 28561
#define NCP (NB*NUM_CL)          // 84
#define ACC_PAD 192              // padded per-(nc,chunk) stage stride
#define SACC_PAD 191             // odd LDS stride for per-problem sums
#define POS_ALPHA 5e-4
#define NBLKA (NB*NUM_CL*PH)     // 14364
#define NROWBLK (NB*PH)          // 684
#define SEGR 43                  // rows per segment (4 segs: 43,43,43,40)

typedef unsigned long long u64;
typedef unsigned int u32;

__device__ __forceinline__ int upIdx(int lo, int hi) {
    return lo*9 - (lo*(lo-1))/2 + (hi - lo);
}
__device__ __forceinline__ int tri(int d, int e) { return d*(d+1)/2 + e; }

__device__ __forceinline__ float wred64(float v) {
    #pragma unroll
    for (int o = 32; o > 0; o >>= 1) v += __shfl_down(v, o, 64);
    return v;
}

// ---------------- Kernel A: fused sigmoid + BCE + 3x3/3 max-pool ----------------
// One block per (n, c, pooled-row ph). int32 labels read directly (L2-resident
// across the 21-class reuse). No global atomics anywhere.
__global__ __launch_bounds__(128) void kernelA(
    const float* __restrict__ logits, const int* __restrict__ labels,
    float* __restrict__ pooledP, unsigned char* __restrict__ pooledL8,
    float* __restrict__ bce_part, u32* __restrict__ cnt_part)
{
    int blk = blockIdx.x;
    int c  = blk % NUM_CL;
    int t2 = blk / NUM_CL;
    int ph = t2 % PH;
    int n  = t2 / PH;
    int tid = threadIdx.x;           // 0..127
    int col0 = tid << 2;

    __shared__ float         svP[W];
    __shared__ unsigned char svL[W];
    __shared__ float         rbce[2];
    __shared__ u32           rcnt[2];

    const float* lgp = logits + (size_t)(n*NUM_CL + c) * (H*W);
    const int*   lbp = labels + (size_t)n * (H*W);

    float vP[4] = {-INFINITY, -INFINITY, -INFINITY, -INFINITY};
    int   vL[4] = {0,0,0,0};
    float bce = 0.f;
    u32 cnt = 0;

    int rbase = 3*ph - 1;
    #pragma unroll
    for (int rr = 0; rr < 3; ++rr) {
        int r = rbase + rr;
        if (r < 0 || r >= H) continue;       // uniform across block
        float4 x4 = *(const float4*)(lgp + (size_t)r*W + col0);
        int4   l4 = *(const int4*)  (lbp + (size_t)r*W + col0);
        float xs[4] = {x4.x, x4.y, x4.z, x4.w};
        int   ls[4] = {l4.x, l4.y, l4.z, l4.w};
        #pragma unroll
        for (int k = 0; k < 4; ++k) {
            int lab = ls[k];
            float x = xs[k];
            float m = (lab < NUM_CL) ? 1.f : 0.f;
            float y = (lab == c) ? 1.f : 0.f;
            float te = __expf(-fabsf(x));
            float u  = 1.f + te;
            float sp = __logf(u);                    // log1p(te)
            float rc = __builtin_amdgcn_rcpf(u);     // 1/(1+te)
            bce += m * (fmaxf(x, 0.f) - x*y + sp);
            float sig = (x >= 0.f) ? rc : te*rc;
            vP[k] = fmaxf(vP[k], sig*m + 1e-6f);
            vL[k] |= (lab == c);
            cnt += (u32)(lab < NUM_CL);
        }
    }

    ((float4*)svP)[tid] = make_float4(vP[0], vP[1], vP[2], vP[3]);
    uchar4 u4;
    u4.x = (unsigned char)vL[0]; u4.y = (unsigned char)vL[1];
    u4.z = (unsigned char)vL[2]; u4.w = (unsigned char)vL[3];
    ((uchar4*)svL)[tid] = u4;

    // wave-level BCE/count reduction (2 waves)
    #pragma unroll
    for (int o = 32; o > 0; o >>= 1) {
        bce += __shfl_down(bce, o, 64);
        cnt += __shfl_down(cnt, o, 64);
    }
    int lane = tid & 63, wv = tid >> 6;
    if (lane == 0) { rbce[wv] = bce; rcnt[wv] = cnt; }
    __syncthreads();

    // horizontal pool from LDS
    size_t rowr = (size_t)(n*NUM_CL + c) * PH + ph;
    #pragma unroll
    for (int pass = 0; pass < 2; ++pass) {
        int pw = tid + pass*128;
        if (pw < PW) {
            int c0 = 3*pw - 1; if (c0 < 0) c0 = 0;
            int c1 = 3*pw + 2; if (c1 > W) c1 = W;
            float pm = -INFINITY;
            int lm = 0;
            for (int qq = c0; qq < c1; ++qq) {
                pm = fmaxf(pm, svP[qq]);
                lm |= svL[qq];
            }
            pooledP [rowr * PWPAD + pw] = pm;
            pooledL8[rowr * PWPAD + pw] = (unsigned char)lm;
        }
    }

    if (tid == 0) {
        bce_part[blk] = rbce[0] + rbce[1];
        if (c == 0) cnt_part[t2] = rcnt[0] + rcnt[1];
    }
}

// ---------------- block reduce (4 waves) + plain store to stage ----------------
template<int CNT>
__device__ __forceinline__ void blockReduceStore(
    float (&v)[CNT], float* __restrict__ stage, int off, bool active,
    int lane, int wave)
{
    __shared__ float red[4][CNT];
    #pragma unroll
    for (int k = 0; k < CNT; ++k) {
        float r = wred64(active ? v[k] : 0.f);
        if (lane == 0) red[wave][k] = r;
    }
    __syncthreads();
    for (int k = (int)threadIdx.x; k < CNT; k += 256) {
        stage[off + k] = red[0][k] + red[1][k] + red[2][k] + red[3][k];
    }
    __syncthreads();
}

// ---------------- Kernel B: rolling-window raw-moment accumulation ----------------
// block = 256 (4 waves); wave = row-segment; lane -> window column j.
// grid = (NCP, 3 col-chunks, 2 groups). Partials -> stage[(nc*3+chunk)*ACC_PAD + k],
// disjoint slots, no atomics, no zero-init required.
__global__ __launch_bounds__(256, 1) void kernelB(
    const float* __restrict__ pooledP, const unsigned char* __restrict__ pooledL8,
    float* __restrict__ stage)
{
    int nc    = blockIdx.x;
    int chunk = blockIdx.y;          // 0..2
    int grp   = blockIdx.z;          // 0..1
    int lane  = threadIdx.x & 63;
    int seg   = threadIdx.x >> 6;    // 0..3
    int j     = chunk*64 + lane;
    bool active = (j < NWW);
    int jc = active ? j : (NWW - 1); // clamped, loads stay in-bounds
    int i0 = seg * SEGR;
    int i1 = (seg == 3) ? NWW : (i0 + SEGR);

    const float* P = pooledP + (size_t)nc * PH * PWPAD + jc;
    const unsigned char* L = pooledL8 + (size_t)nc * PH * PWPAD + jc;
    float* st = stage + (size_t)(nc*3 + chunk) * ACC_PAD;

    float pA[3], pB[3], lA[3], lB[3];
    #pragma unroll
    for (int t = 0; t < 3; ++t) {
        pA[t] = P[(size_t)i0 * PWPAD + t];
        lA[t] = (float)L[(size_t)i0 * PWPAD + t];
        pB[t] = P[(size_t)(i0+1) * PWPAD + t];
        lB[t] = (float)L[(size_t)(i0+1) * PWPAD + t];
    }

    if (grp == 0) {
        float sl[9], sp[9], cll[45], cpp[45];
        #pragma unroll
        for (int d = 0; d < 9; ++d) { sl[d] = 0.f; sp[d] = 0.f; }
        #pragma unroll
        for (int k = 0; k < 45; ++k) { cll[k] = 0.f; cpp[k] = 0.f; }

        for (int i = i0; i < i1; ++i) {
            const float* rp = P + (size_t)(i+2) * PWPAD;
            const unsigned char* rl = L + (size_t)(i+2) * PWPAD;
            float pC[3] = {rp[0], rp[1], rp[2]};
            float lC[3] = {(float)rl[0], (float)rl[1], (float)rl[2]};
            float pv[9] = {pA[0],pA[1],pA[2], pB[0],pB[1],pB[2], pC[0],pC[1],pC[2]};
            float lv[9] = {lA[0],lA[1],lA[2], lB[0],lB[1],lB[2], lC[0],lC[1],lC[2]};
            #pragma unroll
            for (int d = 0; d < 9; ++d) { sp[d] += pv[d]; sl[d] += lv[d]; }
            int k = 0;
            #pragma unroll
            for (int d = 0; d < 9; ++d)
                #pragma unroll
                for (int e = d; e < 9; ++e) {
                    cpp[k] += pv[d]*pv[e];
                    cll[k] += lv[d]*lv[e];
                    ++k;
                }
            #pragma unroll
            for (int t = 0; t < 3; ++t) {
                pA[t] = pB[t]; pB[t] = pC[t];
                lA[t] = lB[t]; lB[t] = lC[t];
            }
        }
        blockReduceStore<9> (sl,  st, 0,  active, lane, seg);
        blockReduceStore<9> (sp,  st, 9,  active, lane, seg);
        blockReduceStore<45>(cll, st, 18, active, lane, seg);
        blockReduceStore<45>(cpp, st, 63, active, lane, seg);
    } else {
        float clp[81];
        #pragma unroll
        for (int k = 0; k < 81; ++k) clp[k] = 0.f;

        for (int i = i0; i < i1; ++i) {
            const float* rp = P + (size_t)(i+2) * PWPAD;
            const unsigned char* rl = L + (size_t)(i+2) * PWPAD;
            float pC[3] = {rp[0], rp[1], rp[2]};
            float lC[3] = {(float)rl[0], (float)rl[1], (float)rl[2]};
            float pv[9] = {pA[0],pA[1],pA[2], pB[0],pB[1],pB[2], pC[0],pC[1],pC[2]};
            float lv[9] = {lA[0],lA[1],lA[2], lB[0],lB[1],lB[2], lC[0],lC[1],lC[2]};
            #pragma unroll
            for (int d = 0; d < 9; ++d)
                #pragma unroll
                for (int e = 0; e < 9; ++e)
                    clp[d*9+e] += lv[d]*pv[e];
            #pragma unroll
            for (int t = 0; t < 3; ++t) {
                pA[t] = pB[t]; pB[t] = pC[t];
                lA[t] = lB[t]; lB[t] = lC[t];
            }
        }
        blockReduceStore<81>(clp, st, 108, active, lane, seg);
    }
}

// ---------------- Kernel C: cooperative LDS staging + per-(n,c) solve + combine ----
__global__ __launch_bounds__(256) void kernelC(
    const float* __restrict__ stage,
    const float* __restrict__ bce_part,
    const u32* __restrict__ cnt_part,
    float* __restrict__ out)
{
    int t = threadIdx.x;

    // LDS copy of the 3-chunk-summed moments: sacc[nc][k], stride 191 (odd)
    __shared__ float sacc[NCP * SACC_PAD];   // 64.2 KB
    __shared__ double sb[256];
    __shared__ u32 sc[256];
    __shared__ float sred[256];

    // cooperative staging: pipelined independent loads, 3-chunk sum in f64
    for (int idx = t; idx < NCP * 189; idx += 256) {
        int p = idx / 189;
        int k = idx - p * 189;
        const float* b = stage + (size_t)p * 3 * ACC_PAD + k;
        double s = (double)b[0] + (double)b[ACC_PAD] + (double)b[2*ACC_PAD];
        sacc[p * SACC_PAD + k] = (float)s;
    }

    // BCE partials: float4 loads (NBLKA = 14364 = 4*3591)
    double bs = 0.0;
    for (int i = t; i < NBLKA/4; i += 256) {
        float4 v = ((const float4*)bce_part)[i];
        bs += (double)v.x + (double)v.y + (double)v.z + (double)v.w;
    }
    u32 cs = 0;
    for (int i = t; i < NROWBLK; i += 256) cs += cnt_part[i];
    sb[t] = bs; sc[t] = cs;
    __syncthreads();
    #pragma unroll
    for (int s = 128; s > 0; s >>= 1) {
        if (t < s) { sb[t] += sb[t + s]; sc[t] += sc[t + s]; }
        __syncthreads();
    }

    float contrib = 0.f;
    if (t < NCP) {
        const float* ac = sacc + t * SACC_PAD;
        const double Minv = 1.0 / (double)M_TOT;
        double Sl[9], Sp[9];
        #pragma unroll
        for (int d = 0; d < 9; ++d) { Sl[d] = (double)ac[d]; Sp[d] = (double)ac[9+d]; }

        float A[45];  // pr_cov + alpha*I (lower tri)
        float G[45];  // la_cov, later appro_var
        float B[81];  // la_pr_cov rows, later W rows
        #pragma unroll
        for (int d = 0; d < 9; ++d) {
            #pragma unroll
            for (int e = 0; e <= d; ++e) {
                int ku = upIdx(e, d);
                double vp = (double)ac[63+ku] - Sp[d]*Sp[e]*Minv;
                double vl = (double)ac[18+ku] - Sl[d]*Sl[e]*Minv;
                if (d == e) vp += POS_ALPHA;
                A[tri(d,e)] = (float)vp;
                G[tri(d,e)] = (float)vl;
            }
        }
        #pragma unroll
        for (int d = 0; d < 9; ++d) {
            #pragma unroll
            for (int e = 0; e < 9; ++e)
                B[d*9+e] = (float)((double)ac[108 + d*9 + e] - Sl[d]*Sp[e]*Minv);
        }

        // Cholesky of A (lower, in place)
        #pragma unroll
        for (int d = 0; d < 9; ++d) {
            float s = A[tri(d,d)];
            #pragma unroll
            for (int f = 0; f < d; ++f) { float v = A[tri(d,f)]; s -= v*v; }
            float ldd = sqrtf(s);
            A[tri(d,d)] = ldd;
            float inv = 1.f / ldd;
            #pragma unroll
            for (int e = d+1; e < 9; ++e) {
                float s2 = A[tri(e,d)];
                #pragma unroll
                for (int f = 0; f < d; ++f) s2 -= A[tri(e,f)] * A[tri(d,f)];
                A[tri(e,d)] = s2 * inv;
            }
        }

        // forward substitution: row d of B <- solve L w = LP[d,:]^T
        #pragma unroll
        for (int d = 0; d < 9; ++d) {
            #pragma unroll
            for (int e = 0; e < 9; ++e) {
                float s = B[d*9+e];
                #pragma unroll
                for (int f = 0; f < e; ++f) s -= A[tri(e,f)] * B[d*9+f];
                B[d*9+e] = s / A[tri(e,e)];
            }
        }

        // appro_var = la_cov - W W^T + alpha*I
        #pragma unroll
        for (int d = 0; d < 9; ++d) {
            #pragma unroll
            for (int g = 0; g <= d; ++g) {
                float qv = 0.f;
                #pragma unroll
                for (int e = 0; e < 9; ++e) qv += B[d*9+e] * B[g*9+e];
                float v = G[tri(d,g)] - qv;
                if (d == g) v += (float)POS_ALPHA;
                G[tri(d,g)] = v;
            }
        }

        // Cholesky of G, sum log(diag + 1e-8)
        float sumlog = 0.f;
        #pragma unroll
        for (int d = 0; d < 9; ++d) {
            float s = G[tri(d,d)];
            #pragma unroll
            for (int f = 0; f < d; ++f) { float v = G[tri(d,f)]; s -= v*v; }
            float ldd = sqrtf(s);
            G[tri(d,d)] = ldd;
            sumlog += logf(ldd + 1e-8f);
            float inv = 1.f / ldd;
            #pragma unroll
            for (int e = d+1; e < 9; ++e) {
                float s2 = G[tri(e,d)];
                #pragma unroll
                for (int f = 0; f < d; ++f) s2 -= G[tri(e,f)] * G[tri(d,f)];
                G[tri(e,d)] = s2 * inv;
            }
        }
        contrib = sumlog * (1.0f / 36.0f);   // /(N * HALF_D) = /(4*9)
    }

    sred[t] = contrib;
    __syncthreads();
    #pragma unroll
    for (int s = 128; s > 0; s >>= 1) {
        if (t < s) sred[t] += sred[t + s];
        __syncthreads();
    }
    if (t == 0) {
        double bce_loss = sb[0] / ((double)sc[0] + 1.0);
        out[0] = (float)(0.5 * bce_loss + 0.5 * (double)sred[0]);
    }
}

extern "C" void kernel_launch(void* const* d_in, const int* in_sizes, int n_in,
                              void* d_out, int out_size, void* d_ws, size_t ws_size,
                              hipStream_t stream)
{
    (void)in_sizes; (void)n_in; (void)out_size; (void)ws_size;
    const float* logits = (const float*)d_in[0];
    const int*   labels = (const int*)d_in[1];
    float* out = (float*)d_out;

    uint8_t* w = (uint8_t*)d_ws;
    size_t off = 0;
    float* stage = (float*)(w + off);          off += (size_t)NCP * 3 * ACC_PAD * 4; // 193536
    float* bce_part = (float*)(w + off);       off += (size_t)NBLKA * 4;             // 57456
    u32* cnt_part = (u32*)(w + off);           off += (size_t)NROWBLK * 4;           // 2736
    off = (off + 15) & ~(size_t)15;
    float* pooledP = (float*)(w + off);        off += (size_t)NCP * PH * PWPAD * 4;  // 10.1 MB
    unsigned char* pooledL8 = (unsigned char*)(w + off); off += (size_t)NCP * PH * PWPAD; // 2.5 MB

    kernelA<<<NBLKA, 128, 0, stream>>>(logits, labels, pooledP, pooledL8, bce_part, cnt_part);
    kernelB<<<dim3(NCP, 3, 2), 256, 0, stream>>>(pooledP, pooledL8, stage);
    kernelC<<<1, 256, 0, stream>>>(stage, bce_part, cnt_part, out);
}